// Round 7
// baseline (500.216 us; speedup 1.0000x reference)
//
#include <hip/hip_runtime.h>

// StyleGAN 3D upsample x2, k=[1,4,6,4,1]/16*2 per axis, fused polyphase:
//   even: o[2i]   = 0.5*(x[i-1]+x[i])
//   odd : o[2i+1] = 0.125*x[i-1] + 0.75*x[i] + 0.125*x[i+1]
// Input fp32 [4,32,48,48,48], output fp32 [4,32,96,96,96].
//
// v7 (resubmit; round-6 run died to container infra, not the kernel):
// FILL-LIKE WRITE LOCALITY. Block = (nc, 4-input-layer slab) -> writes
// 8 complete, contiguous output planes (295 KB sequential region),
// plane-by-plane. Full 48x48 input planes staged in LDS (6 layers incl.
// D-halo, zero-padded H/W halos; 62.4 KB). Each thread owns 6 output rows
// (oh = ty+16r, fixed H-parity) x 4 W-outputs and slides the D window in
// registers. All per-r loops unrolled (static indexing, no scratch).

#define IN_D 48
#define IN_H 48
#define IN_W 48
#define NC   128
#define TD   4                 // input layers advanced per block -> 8 out planes
#define NTX  24
#define NTY  16
#define NTHREADS (NTX * NTY)   // 384 = 6 waves
#define LZ  (TD + 2)           // 6 staged layers (D halo)
#define LYS 50                 // y=0 zero | 1..48 = input rows 0..47 | 49 zero
#define LXP 52                 // col0 zero | 1..48 = input cols | 49 zero | pad
#define NR  6                  // output rows per thread
#define OWD 96
#define PLANE (96 * 96)        // output plane, floats

__device__ __forceinline__ float4 f4_even(float4 a, float4 b) {
    return make_float4(0.5f * (a.x + b.x), 0.5f * (a.y + b.y),
                       0.5f * (a.z + b.z), 0.5f * (a.w + b.w));
}
__device__ __forceinline__ float4 f4_odd(float4 a, float4 b, float4 c) {
    return make_float4(0.125f * (a.x + c.x) + 0.75f * b.x,
                       0.125f * (a.y + c.y) + 0.75f * b.y,
                       0.125f * (a.z + c.z) + 0.75f * b.z,
                       0.125f * (a.w + c.w) + 0.75f * b.w);
}

__global__ __launch_bounds__(NTHREADS)
void upfir3d_kernel(const float* __restrict__ in,
                    float* __restrict__ out) {
    __shared__ float lds[LZ * LYS * LXP];  // 6*50*52*4 = 62400 B

    const int tx = threadIdx.x;            // 0..23
    const int ty = threadIdx.y;            // 0..15
    const int dz = blockIdx.x;             // 0..11
    const int nc = blockIdx.y;             // 0..127
    const int id0 = dz * TD;
    const float* inb = in + (size_t)nc * (IN_D * IN_H * IN_W);
    const int tid = ty * NTX + tx;

    // ---- zero H-halo rows (y=0 and y=49, full width) ----
    for (int idx = tid; idx < LZ * 2 * LXP; idx += NTHREADS) {
        int z   = idx / (2 * LXP);
        int rem = idx - z * (2 * LXP);
        int y   = (rem < LXP) ? 0 : (LYS - 1);
        int col = (rem < LXP) ? rem : rem - LXP;
        lds[(z * LYS + y) * LXP + col] = 0.0f;
    }
    // ---- zero W-halo cols (col 0 and 49) of interior rows ----
    for (int idx = tid; idx < LZ * IN_H * 2; idx += NTHREADS) {
        int z   = idx / (IN_H * 2);
        int rem = idx - z * (IN_H * 2);
        int y   = 1 + (rem >> 1);
        int col = (rem & 1) ? 49 : 0;
        lds[(z * LYS + y) * LXP + col] = 0.0f;
    }
    // ---- stage interior: 12 float4 per input row, zero OOB D layers ----
    for (int idx = tid; idx < LZ * IN_H * 12; idx += NTHREADS) {   // 9 iters
        int q  = idx % 12;
        int rf = idx / 12;
        int z  = rf / IN_H;
        int y  = rf - z * IN_H;
        int gd = id0 - 1 + z;
        float4 v = make_float4(0.f, 0.f, 0.f, 0.f);
        if ((unsigned)gd < (unsigned)IN_D)
            v = *reinterpret_cast<const float4*>(
                    inb + ((size_t)gd * IN_H + y) * IN_W + 4 * q);
        float* dst = &lds[(z * LYS + 1 + y) * LXP + 1 + 4 * q];
        dst[0] = v.x; dst[1] = v.y; dst[2] = v.z; dst[3] = v.w;
    }
    __syncthreads();

    // ---- per-thread: 6 output rows (oh = ty + 16r, fixed parity), slide D ----
    const int p = ty & 1;
    const float wga = p ? 0.125f : 0.5f;   // input row j-1
    const float wgb = p ? 0.75f  : 0.5f;   // input row j
    const float wgc = p ? 0.125f : 0.0f;   // input row j+1
    const int yb = ty >> 1;                // j for r=0; +8 per r
    const int cx = 2 * tx;                 // LDS col of input col 2tx-1

    // WH-filter one staged layer z for output row r: 4 W-outputs.
    auto whpart = [&](int z, int r) -> float4 {
        const float* pp = &lds[(z * LYS + yb + 8 * r) * LXP + cx];
        float4 q4 = make_float4(0.f, 0.f, 0.f, 0.f);
#pragma unroll
        for (int dy = 0; dy < 3; ++dy) {
            const float wt = (dy == 0) ? wga : (dy == 1) ? wgb : wgc;
            float2 a = *reinterpret_cast<const float2*>(pp + dy * LXP);
            float2 b = *reinterpret_cast<const float2*>(pp + dy * LXP + 2);
            q4.x += wt * (0.5f   * (a.x + a.y));
            q4.y += wt * (0.125f * (a.x + b.x) + 0.75f * a.y);
            q4.z += wt * (0.5f   * (a.y + b.x));
            q4.w += wt * (0.125f * (a.y + b.y) + 0.75f * b.x);
        }
        return q4;
    };

    float4 qm[NR], qc[NR];
#pragma unroll
    for (int r = 0; r < NR; ++r) qm[r] = whpart(0, r);   // layer id0-1
#pragma unroll
    for (int r = 0; r < NR; ++r) qc[r] = whpart(1, r);   // layer id0

    float* ob = out + (size_t)nc * (96 * PLANE);
    const unsigned robase = (unsigned)(ty * OWD + 4 * tx);

#pragma unroll
    for (int d = 0; d < TD; ++d) {
        float4 qp[NR];
#pragma unroll
        for (int r = 0; r < NR; ++r) qp[r] = whpart(d + 2, r);

        const unsigned pe = (unsigned)((8 * dz + 2 * d) * PLANE);
        // even plane: full plane written by the block in one burst
#pragma unroll
        for (int r = 0; r < NR; ++r)
            *reinterpret_cast<float4*>(ob + pe + robase + 1536u * r)
                = f4_even(qm[r], qc[r]);
        // odd plane next (block-sequential)
#pragma unroll
        for (int r = 0; r < NR; ++r)
            *reinterpret_cast<float4*>(ob + pe + PLANE + robase + 1536u * r)
                = f4_odd(qm[r], qc[r], qp[r]);

#pragma unroll
        for (int r = 0; r < NR; ++r) { qm[r] = qc[r]; qc[r] = qp[r]; }
    }
}

extern "C" void kernel_launch(void* const* d_in, const int* in_sizes, int n_in,
                              void* d_out, int out_size, void* d_ws, size_t ws_size,
                              hipStream_t stream) {
    const float* x = (const float*)d_in[0];
    float* out = (float*)d_out;

    dim3 grid(IN_D / TD, NC, 1);           // (12, 128) = 1536 blocks
    dim3 block(NTX, NTY, 1);               // (24, 16) = 384 threads
    upfir3d_kernel<<<grid, block, 0, stream>>>(x, out);
}